// Round 2
// baseline (1024.912 us; speedup 1.0000x reference)
//
#include <hip/hip_runtime.h>
#include <math.h>

#define NEG_SLOPE 0.2f
#define NPB 256   // nodes per bucket (dst >> 8)
#define MAXB 512  // max buckets => supports n_nodes <= 131072 (bench: 100000 -> 391)
#define A1_BS 512

static __device__ __forceinline__ float leaky(float x) { return fmaxf(x, NEG_SLOPE * x); }

// ---------------- misc ----------------
__global__ void k_zero(int* p, int n) {
    int i = blockIdx.x * blockDim.x + threadIdx.x;
    if (i < n) p[i] = 0;
}

// ---------------- bucketed counting sort CSR build ----------------
// Buckets = 256-node ranges. All heavy atomics are LDS-local; all heavy global
// writes are to per-block-exclusive contiguous ranges (lines fill while
// L2-resident). CSR is SoA (csr_src / csr_ew) so k_edge's pipeline can retire
// the src registers at gather-issue time (register pressure).

// Pass A0: global bucket histogram (LDS pre-aggregated).
__global__ __launch_bounds__(256) void k_bcount(const int* __restrict__ dst,
                                                int* __restrict__ bcnt, int n_edges, int nb) {
    __shared__ int h[MAXB];
    for (int i = threadIdx.x; i < nb; i += blockDim.x) h[i] = 0;
    __syncthreads();
    int stride = gridDim.x * blockDim.x;
    for (int e = blockIdx.x * blockDim.x + threadIdx.x; e < n_edges; e += stride)
        atomicAdd(&h[dst[e] >> 8], 1);
    __syncthreads();
    for (int i = threadIdx.x; i < nb; i += blockDim.x)
        if (h[i]) atomicAdd(&bcnt[i], h[i]);
}

// Bucket exclusive scan (nb <= MAXB, single block).
__global__ __launch_bounds__(MAXB) void k_bscan(const int* __restrict__ bcnt,
                                                int* __restrict__ boffB,
                                                int* __restrict__ bcur, int nb) {
    __shared__ int s[MAXB];
    int t = threadIdx.x;
    int v = (t < nb) ? bcnt[t] : 0;
    s[t] = v;
    __syncthreads();
    for (int off = 1; off < MAXB; off <<= 1) {
        int x = (t >= off) ? s[t - off] : 0;
        __syncthreads();
        s[t] += x;
        __syncthreads();
    }
    if (t < nb) {
        int ex = s[t] - v;
        boffB[t] = ex;
        bcur[t] = ex;
    }
}

// Pass A1: bin edges into bucket-grouped SoA staging. Each block counts its
// chunk per bucket in LDS, reserves a contiguous exclusive slice per bucket
// (one global atomic per block x bucket), then writes dense into its slices.
__global__ __launch_bounds__(A1_BS) void k_bin(const int* __restrict__ src,
                                               const int* __restrict__ dst,
                                               const float* __restrict__ ew,
                                               int* __restrict__ bcur,
                                               int* __restrict__ dstS,
                                               int* __restrict__ srcS,
                                               float* __restrict__ ewS,
                                               int n_edges, int chunk, int nb) {
    __shared__ int cnt[MAXB];
    __shared__ int base[MAXB];
    int t = threadIdx.x;
    int e0 = blockIdx.x * chunk;
    int e1 = e0 + chunk;
    if (e1 > n_edges) e1 = n_edges;
    for (int i = t; i < nb; i += A1_BS) cnt[i] = 0;
    __syncthreads();
    for (int e = e0 + t; e < e1; e += A1_BS) atomicAdd(&cnt[dst[e] >> 8], 1);
    __syncthreads();
    for (int i = t; i < nb; i += A1_BS) {
        int c = cnt[i];
        base[i] = c ? atomicAdd(&bcur[i], c) : 0;
        cnt[i] = 0;  // reuse as local rank cursor
    }
    __syncthreads();
    for (int e = e0 + t; e < e1; e += A1_BS) {
        int d = dst[e];
        int b = d >> 8;
        int p = base[b] + atomicAdd(&cnt[b], 1);
        dstS[p] = d;
        srcS[p] = src[e];
        ewS[p] = ew[e];
    }
}

// Pass B (fused): per-bucket degree hist -> in-LDS scan -> row_ptr -> placement.
// One block owns its 256-node range exclusively: zero global atomics; csr
// writes land in a block-exclusive ~65KB window (full-line L2-local
// writebacks). Replaces k_deg + scan1/2/3 + k_place (4 fewer dispatches, one
// fewer pass over staging).
__global__ __launch_bounds__(NPB) void k_buildcsr(const int* __restrict__ boffB,
                                                  const int* __restrict__ bcnt,
                                                  const int* __restrict__ dstS,
                                                  const int* __restrict__ srcS,
                                                  const float* __restrict__ ewS,
                                                  int* __restrict__ row_ptr,
                                                  int* __restrict__ csr_src,
                                                  float* __restrict__ csr_ew,
                                                  int n_nodes, int n_edges) {
    __shared__ int hist[NPB];
    __shared__ int pre[NPB];
    int b = blockIdx.x;
    int t = threadIdx.x;
    hist[t] = 0;
    __syncthreads();
    int off = boffB[b];
    int end = off + bcnt[b];
    for (int i = off + t; i < end; i += NPB) atomicAdd(&hist[dstS[i] & (NPB - 1)], 1);
    __syncthreads();
    int v = hist[t];
    pre[t] = v;
    __syncthreads();
    for (int o = 1; o < NPB; o <<= 1) {
        int x = (t >= o) ? pre[t - o] : 0;
        __syncthreads();
        pre[t] += x;
        __syncthreads();
    }
    int ex = pre[t] - v;  // exclusive in-bucket prefix
    int node = b * NPB + t;
    if (node < n_nodes) row_ptr[node] = off + ex;
    if (node == n_nodes - 1) row_ptr[n_nodes] = n_edges;
    // zero pad so k_edge's clamped tail reads (deg-0 last nodes) are safe
    if (b == 0 && t < 4) {
        csr_src[n_edges + t] = 0;
        csr_ew[n_edges + t] = 0.f;
    }
    hist[t] = off + ex;  // reuse as cursor
    __syncthreads();
    for (int i = off + t; i < end; i += NPB) {
        int d = dstS[i];
        int p = atomicAdd(&hist[d & (NPB - 1)], 1);
        csr_src[p] = srcS[i];
        csr_ew[p] = ewS[i];
    }
}

// ---------------- GEMM + fused attention scores (streamed A) ----------------
__global__ __launch_bounds__(256) void k_gemm(const float* __restrict__ A,
                                              const float* __restrict__ B,
                                              float* __restrict__ C,
                                              const float* __restrict__ al,
                                              const float* __restrict__ ar,
                                              float* __restrict__ el,
                                              float* __restrict__ er, int n) {
    __shared__ float Bs[128 * 64];  // Bs[k][c]
    int t = threadIdx.x;
    int row0 = blockIdx.x * 64;
    int colbase = blockIdx.y * 64;

    // stage B strip
    {
        int c0 = (t & 15) * 4;
        int kr = t >> 4;  // 0..15
        for (int it = 0; it < 8; ++it) {
            int k = kr + it * 16;
            float4 v = *(const float4*)(B + (size_t)k * 128 + colbase + c0);
            *(float4*)(Bs + k * 64 + c0) = v;
        }
    }
    __syncthreads();

    int r0 = row0 + (t >> 4) * 4;
    int c0 = (t & 15) * 4;
    const float* Ar0 = A + (size_t)((r0 + 0) < n ? (r0 + 0) : 0) * 128;
    const float* Ar1 = A + (size_t)((r0 + 1) < n ? (r0 + 1) : 0) * 128;
    const float* Ar2 = A + (size_t)((r0 + 2) < n ? (r0 + 2) : 0) * 128;
    const float* Ar3 = A + (size_t)((r0 + 3) < n ? (r0 + 3) : 0) * 128;

    float acc[4][4];
#pragma unroll
    for (int i = 0; i < 4; i++)
#pragma unroll
        for (int j = 0; j < 4; j++) acc[i][j] = 0.f;

#pragma unroll 2
    for (int k = 0; k < 128; k += 4) {
        float4 a0 = *(const float4*)(Ar0 + k);
        float4 a1 = *(const float4*)(Ar1 + k);
        float4 a2 = *(const float4*)(Ar2 + k);
        float4 a3 = *(const float4*)(Ar3 + k);
#pragma unroll
        for (int kk = 0; kk < 4; kk++) {
            float4 b = *(const float4*)(Bs + (k + kk) * 64 + c0);
            float e0 = kk == 0 ? a0.x : kk == 1 ? a0.y : kk == 2 ? a0.z : a0.w;
            float e1 = kk == 0 ? a1.x : kk == 1 ? a1.y : kk == 2 ? a1.z : a1.w;
            float e2 = kk == 0 ? a2.x : kk == 1 ? a2.y : kk == 2 ? a2.z : a2.w;
            float e3 = kk == 0 ? a3.x : kk == 1 ? a3.y : kk == 2 ? a3.z : a3.w;
            acc[0][0] = fmaf(e0, b.x, acc[0][0]); acc[0][1] = fmaf(e0, b.y, acc[0][1]);
            acc[0][2] = fmaf(e0, b.z, acc[0][2]); acc[0][3] = fmaf(e0, b.w, acc[0][3]);
            acc[1][0] = fmaf(e1, b.x, acc[1][0]); acc[1][1] = fmaf(e1, b.y, acc[1][1]);
            acc[1][2] = fmaf(e1, b.z, acc[1][2]); acc[1][3] = fmaf(e1, b.w, acc[1][3]);
            acc[2][0] = fmaf(e2, b.x, acc[2][0]); acc[2][1] = fmaf(e2, b.y, acc[2][1]);
            acc[2][2] = fmaf(e2, b.z, acc[2][2]); acc[2][3] = fmaf(e2, b.w, acc[2][3]);
            acc[3][0] = fmaf(e3, b.x, acc[3][0]); acc[3][1] = fmaf(e3, b.y, acc[3][1]);
            acc[3][2] = fmaf(e3, b.z, acc[3][2]); acc[3][3] = fmaf(e3, b.w, acc[3][3]);
        }
    }

#pragma unroll
    for (int i = 0; i < 4; i++) {
        int r = r0 + i;
        if (r < n) {
            float4 v = make_float4(acc[i][0], acc[i][1], acc[i][2], acc[i][3]);
            *(float4*)(C + (size_t)r * 128 + colbase + c0) = v;
        }
    }

    // fused el/er: strip covers heads 2*by, 2*by+1; 8 consecutive lanes share
    // (row group, head) -> shfl reduce.
    {
        int hg = blockIdx.y * 2 + ((t >> 3) & 1);
        float4 a4 = *(const float4*)(al + hg * 32 + (t & 7) * 4);
        float4 b4 = *(const float4*)(ar + hg * 32 + (t & 7) * 4);
        float pel[4], per[4];
#pragma unroll
        for (int i = 0; i < 4; i++) {
            pel[i] = acc[i][0] * a4.x + acc[i][1] * a4.y + acc[i][2] * a4.z + acc[i][3] * a4.w;
            per[i] = acc[i][0] * b4.x + acc[i][1] * b4.y + acc[i][2] * b4.z + acc[i][3] * b4.w;
        }
#pragma unroll
        for (int m = 1; m < 8; m <<= 1) {
#pragma unroll
            for (int i = 0; i < 4; i++) {
                pel[i] += __shfl_xor(pel[i], m);
                per[i] += __shfl_xor(per[i], m);
            }
        }
        if ((t & 7) == 0) {
#pragma unroll
            for (int i = 0; i < 4; i++) {
                int r = r0 + i;
                if (r < n) {
                    el[(size_t)r * 4 + hg] = pel[i];
                    er[(size_t)r * 4 + hg] = per[i];
                }
            }
        }
    }
}

// ---------------- per-dst-node softmax + aggregate (2-deep SW pipeline) ----
// TWO nodes per wave (32-lane halves). Latency-bound before (VALUBusy 28%,
// fetch BW 3.8 TB/s, VGPR 28): each iter serialized csr-wait + gather-wait.
// Now ping-pong register sets: while computing group j, group j+1's el/feat
// gathers are in flight and group j+2's sequential csr loads are issued.
// Issue order SRC(j+2) -> GATH(j+1) -> COMP(j) -> EW(j+2) keeps every
// s_waitcnt a counted partial wait (needed data is always oldest outstanding).
__global__ __launch_bounds__(256) void k_edge(const int* __restrict__ row_ptr,
                                              const int* __restrict__ csr_src,
                                              const float* __restrict__ csr_ew,
                                              const float* __restrict__ feat,
                                              const float* __restrict__ el,
                                              const float* __restrict__ er,
                                              const float* __restrict__ bias,
                                              float* __restrict__ out, int n) {
    int wv = threadIdx.x >> 6;
    int lane = threadIdx.x & 63;
    int sub = lane >> 5;   // which node of this wave's pair
    int li = lane & 31;    // feature lane
    int h = li >> 3;       // head
    int v = blockIdx.x * 8 + wv * 2 + sub;
    bool active = v < n;
    int vc = active ? v : n - 1;

    int start = row_ptr[vc];
    int end = active ? row_ptr[vc + 1] : start;
    float er_h = er[(size_t)vc * 4 + h];

    int myT = (end - start + 3) >> 2;
    int otherT = __shfl(myT, lane ^ 32);
    int maxT = myT > otherT ? myT : otherT;

    int last = end - 1;
    if (last < start) last = start;  // deg-0 half: clamped reads (csr pad is zeroed)

    float4 acc = make_float4(0.f, 0.f, 0.f, 0.f);
    float ssum = 0.f;
    const float4* feat4 = (const float4*)feat;

#define SRCL(J, S0, S1, S2, S3)                                     \
    {                                                               \
        int i_ = start + (J) * 4;                                   \
        int i0_ = i_ < last ? i_ : last;                            \
        int i1_ = i_ + 1 < last ? i_ + 1 : last;                    \
        int i2_ = i_ + 2 < last ? i_ + 2 : last;                    \
        int i3_ = i_ + 3 < last ? i_ + 3 : last;                    \
        S0 = csr_src[i0_]; S1 = csr_src[i1_];                       \
        S2 = csr_src[i2_]; S3 = csr_src[i3_];                       \
    }

#define EWL(J, W0, W1, W2, W3)                                      \
    {                                                               \
        int i_ = start + (J) * 4;                                   \
        int i0_ = i_ < last ? i_ : last;                            \
        int i1_ = i_ + 1 < last ? i_ + 1 : last;                    \
        int i2_ = i_ + 2 < last ? i_ + 2 : last;                    \
        int i3_ = i_ + 3 < last ? i_ + 3 : last;                    \
        W0 = csr_ew[i0_]; W1 = csr_ew[i1_];                         \
        W2 = csr_ew[i2_]; W3 = csr_ew[i3_];                         \
    }

#define GATH(S0, S1, S2, S3, E0, E1, E2, E3, F0, F1, F2, F3)        \
    {                                                               \
        E0 = el[(size_t)S0 * 4 + h]; E1 = el[(size_t)S1 * 4 + h];   \
        E2 = el[(size_t)S2 * 4 + h]; E3 = el[(size_t)S3 * 4 + h];   \
        F0 = feat4[(size_t)S0 * 32 + li];                           \
        F1 = feat4[(size_t)S1 * 32 + li];                           \
        F2 = feat4[(size_t)S2 * 32 + li];                           \
        F3 = feat4[(size_t)S3 * 32 + li];                           \
    }

#define COMPG(J, W0, W1, W2, W3, E0, E1, E2, E3, F0, F1, F2, F3)    \
    {                                                               \
        int i_ = start + (J) * 4;                                   \
        float p0 = (i_ < end) ? __expf(leaky(E0 + er_h)) : 0.f;     \
        float p1 = (i_ + 1 < end) ? __expf(leaky(E1 + er_h)) : 0.f; \
        float p2 = (i_ + 2 < end) ? __expf(leaky(E2 + er_h)) : 0.f; \
        float p3 = (i_ + 3 < end) ? __expf(leaky(E3 + er_h)) : 0.f; \
        ssum += (p0 + p1) + (p2 + p3);                              \
        float w0 = p0 * W0, w1 = p1 * W1;                           \
        float w2 = p2 * W2, w3 = p3 * W3;                           \
        acc.x = fmaf(w0, F0.x, acc.x); acc.y = fmaf(w0, F0.y, acc.y); \
        acc.z = fmaf(w0, F0.z, acc.z); acc.w = fmaf(w0, F0.w, acc.w); \
        acc.x = fmaf(w1, F1.x, acc.x); acc.y = fmaf(w1, F1.y, acc.y); \
        acc.z = fmaf(w1, F1.z, acc.z); acc.w = fmaf(w1, F1.w, acc.w); \
        acc.x = fmaf(w2, F2.x, acc.x); acc.y = fmaf(w2, F2.y, acc.y); \
        acc.z = fmaf(w2, F2.z, acc.z); acc.w = fmaf(w2, F2.w, acc.w); \
        acc.x = fmaf(w3, F3.x, acc.x); acc.y = fmaf(w3, F3.y, acc.y); \
        acc.z = fmaf(w3, F3.z, acc.z); acc.w = fmaf(w3, F3.w, acc.w); \
    }

    int as0, as1, as2, as3, bs0, bs1, bs2, bs3;
    float aw0, aw1, aw2, aw3, bw0, bw1, bw2, bw3;
    float ae0, ae1, ae2, ae3, be0, be1, be2, be3;
    float4 af0, af1, af2, af3, bf0, bf1, bf2, bf3;

    // prologue: group 0 fully staged, group 1 csr staged (clamped => always safe)
    SRCL(0, as0, as1, as2, as3);
    EWL(0, aw0, aw1, aw2, aw3);
    GATH(as0, as1, as2, as3, ae0, ae1, ae2, ae3, af0, af1, af2, af3);
    SRCL(1, bs0, bs1, bs2, bs3);
    EWL(1, bw0, bw1, bw2, bw3);

    int j = 0;
    while (true) {
        SRCL(j + 2, as0, as1, as2, as3);
        GATH(bs0, bs1, bs2, bs3, be0, be1, be2, be3, bf0, bf1, bf2, bf3);
        COMPG(j, aw0, aw1, aw2, aw3, ae0, ae1, ae2, ae3, af0, af1, af2, af3);
        EWL(j + 2, aw0, aw1, aw2, aw3);
        ++j;
        if (j >= maxT) break;
        SRCL(j + 2, bs0, bs1, bs2, bs3);
        GATH(as0, as1, as2, as3, ae0, ae1, ae2, ae3, af0, af1, af2, af3);
        COMPG(j, bw0, bw1, bw2, bw3, be0, be1, be2, be3, bf0, bf1, bf2, bf3);
        EWL(j + 2, bw0, bw1, bw2, bw3);
        ++j;
        if (j >= maxT) break;
    }

#undef SRCL
#undef EWL
#undef GATH
#undef COMPG

    if (active) {
        float inv = 1.f / fmaxf(ssum, 1e-20f);
        float4 bv = *(const float4*)(bias + li * 4);
        float o0 = fmaf(acc.x, inv, bv.x);
        float o1 = fmaf(acc.y, inv, bv.y);
        float o2 = fmaf(acc.z, inv, bv.z);
        float o3 = fmaf(acc.w, inv, bv.w);
        o0 = o0 > 0.f ? o0 : __expf(o0) - 1.f;
        o1 = o1 > 0.f ? o1 : __expf(o1) - 1.f;
        o2 = o2 > 0.f ? o2 : __expf(o2) - 1.f;
        o3 = o3 > 0.f ? o3 : __expf(o3) - 1.f;
        *(float4*)(out + (size_t)v * 128 + li * 4) = make_float4(o0, o1, o2, o3);
    }
}

// ---------------- launch ----------------
extern "C" void kernel_launch(void* const* d_in, const int* in_sizes, int n_in,
                              void* d_out, int out_size, void* d_ws, size_t ws_size,
                              hipStream_t stream) {
    int n_nodes = in_sizes[0] / 128;
    int n_edges = in_sizes[1];

    const float* in_feat = (const float*)d_in[0];
    const float* ew = (const float*)d_in[1];
    const int* src = (const int*)d_in[2];
    const int* dst = (const int*)d_in[3];
    const float* W0 = (const float*)d_in[4];
    const float* al0 = (const float*)d_in[5];
    const float* ar0 = (const float*)d_in[6];
    const float* b0 = (const float*)d_in[7];
    const float* W1 = (const float*)d_in[8];
    const float* al1 = (const float*)d_in[9];
    const float* ar1 = (const float*)d_in[10];
    const float* b1 = (const float*)d_in[11];
    float* out = (float*)d_out;

    char* w = (char*)d_ws;
    auto alloc = [&](size_t bytes) {
        char* p = w;
        w += (bytes + 255) & ~(size_t)255;
        return p;
    };
    float* feat = (float*)alloc((size_t)n_nodes * 128 * 4);
    float* h1 = (float*)alloc((size_t)n_nodes * 128 * 4);
    float* el = (float*)alloc((size_t)n_nodes * 4 * 4);
    float* er = (float*)alloc((size_t)n_nodes * 4 * 4);
    int* row_ptr = (int*)alloc(((size_t)n_nodes + 1) * 4);
    int* bcnt = (int*)alloc(MAXB * 4);
    int* boffB = (int*)alloc(MAXB * 4);
    int* bcur = (int*)alloc(MAXB * 4);
    int* csr_src = (int*)alloc((size_t)n_edges * 4 + 256);   // +pad for clamped tail reads
    float* csr_ew = (float*)alloc((size_t)n_edges * 4 + 256);

    // SoA staging overlays feat: staging (written k_bin, read k_buildcsr) is
    // dead before k_gemm writes feat (stream-ordered). 3*E*4 = 38.4MB <= 51.2MB.
    int* dstS = (int*)feat;
    int* srcS = dstS + n_edges;
    float* ewS = (float*)(srcS + n_edges);

    int tb = 256;
    int nb2 = (n_nodes + NPB - 1) / NPB;  // buckets (<= MAXB for n<=131072)

    // CSR build: bucketed counting sort (rebuilt every call)
    k_zero<<<(MAXB + tb - 1) / tb, tb, 0, stream>>>(bcnt, nb2);
    k_bcount<<<256, tb, 0, stream>>>(dst, bcnt, n_edges, nb2);
    k_bscan<<<1, MAXB, 0, stream>>>(bcnt, boffB, bcur, nb2);
    int a1_grid = 256;
    int chunk = (n_edges + a1_grid - 1) / a1_grid;
    k_bin<<<a1_grid, A1_BS, 0, stream>>>(src, dst, ew, bcur, dstS, srcS, ewS, n_edges, chunk, nb2);
    k_buildcsr<<<nb2, NPB, 0, stream>>>(boffB, bcnt, dstS, srcS, ewS, row_ptr, csr_src, csr_ew,
                                        n_nodes, n_edges);

    dim3 gg((n_nodes + 63) / 64, 2);
    int ge = (n_nodes + 7) / 8;

    // layer 1
    k_gemm<<<gg, 256, 0, stream>>>(in_feat, W0, feat, al0, ar0, el, er, n_nodes);
    k_edge<<<ge, 256, 0, stream>>>(row_ptr, csr_src, csr_ew, feat, el, er, b0, h1, n_nodes);

    // layer 2
    k_gemm<<<gg, 256, 0, stream>>>(h1, W1, feat, al1, ar1, el, er, n_nodes);
    k_edge<<<ge, 256, 0, stream>>>(row_ptr, csr_src, csr_ew, feat, el, er, b1, out, n_nodes);
}

// Round 3
// 1006.791 us; speedup vs baseline: 1.0180x; 1.0180x over previous
//
#include <hip/hip_runtime.h>
#include <math.h>

#define NEG_SLOPE 0.2f
#define NPB 256   // nodes per bucket (dst >> 8)
#define MAXB 512  // max buckets => supports n_nodes <= 131072 (bench: 100000 -> 391)
#define A1_BS 512

static __device__ __forceinline__ float leaky(float x) { return fmaxf(x, NEG_SLOPE * x); }

// ---------------- misc ----------------
__global__ void k_zero(int* p, int n) {
    int i = blockIdx.x * blockDim.x + threadIdx.x;
    if (i < n) p[i] = 0;
}

// ---------------- bucketed counting sort CSR build ----------------
// Buckets = 256-node ranges. All heavy atomics are LDS-local; all heavy global
// writes are to per-block-exclusive contiguous ranges (lines fill while
// L2-resident). CSR is AoS int2 (src, ew-bits): one 8B load per edge in
// k_edge (SoA split cost +19MB FETCH in round 2 — reverted).

// Pass A0: global bucket histogram (LDS pre-aggregated).
__global__ __launch_bounds__(256) void k_bcount(const int* __restrict__ dst,
                                                int* __restrict__ bcnt, int n_edges, int nb) {
    __shared__ int h[MAXB];
    for (int i = threadIdx.x; i < nb; i += blockDim.x) h[i] = 0;
    __syncthreads();
    int stride = gridDim.x * blockDim.x;
    for (int e = blockIdx.x * blockDim.x + threadIdx.x; e < n_edges; e += stride)
        atomicAdd(&h[dst[e] >> 8], 1);
    __syncthreads();
    for (int i = threadIdx.x; i < nb; i += blockDim.x)
        if (h[i]) atomicAdd(&bcnt[i], h[i]);
}

// Bucket exclusive scan (nb <= MAXB, single block).
__global__ __launch_bounds__(MAXB) void k_bscan(const int* __restrict__ bcnt,
                                                int* __restrict__ boffB,
                                                int* __restrict__ bcur, int nb) {
    __shared__ int s[MAXB];
    int t = threadIdx.x;
    int v = (t < nb) ? bcnt[t] : 0;
    s[t] = v;
    __syncthreads();
    for (int off = 1; off < MAXB; off <<= 1) {
        int x = (t >= off) ? s[t - off] : 0;
        __syncthreads();
        s[t] += x;
        __syncthreads();
    }
    if (t < nb) {
        int ex = s[t] - v;
        boffB[t] = ex;
        bcur[t] = ex;
    }
}

// Pass A1: bin edges into bucket-grouped SoA staging. Each block counts its
// chunk per bucket in LDS, reserves a contiguous exclusive slice per bucket
// (one global atomic per block x bucket), then writes dense into its slices.
__global__ __launch_bounds__(A1_BS) void k_bin(const int* __restrict__ src,
                                               const int* __restrict__ dst,
                                               const float* __restrict__ ew,
                                               int* __restrict__ bcur,
                                               int* __restrict__ dstS,
                                               int* __restrict__ srcS,
                                               float* __restrict__ ewS,
                                               int n_edges, int chunk, int nb) {
    __shared__ int cnt[MAXB];
    __shared__ int base[MAXB];
    int t = threadIdx.x;
    int e0 = blockIdx.x * chunk;
    int e1 = e0 + chunk;
    if (e1 > n_edges) e1 = n_edges;
    for (int i = t; i < nb; i += A1_BS) cnt[i] = 0;
    __syncthreads();
    for (int e = e0 + t; e < e1; e += A1_BS) atomicAdd(&cnt[dst[e] >> 8], 1);
    __syncthreads();
    for (int i = t; i < nb; i += A1_BS) {
        int c = cnt[i];
        base[i] = c ? atomicAdd(&bcur[i], c) : 0;
        cnt[i] = 0;  // reuse as local rank cursor
    }
    __syncthreads();
    for (int e = e0 + t; e < e1; e += A1_BS) {
        int d = dst[e];
        int b = d >> 8;
        int p = base[b] + atomicAdd(&cnt[b], 1);
        dstS[p] = d;
        srcS[p] = src[e];
        ewS[p] = ew[e];
    }
}

// Pass B (fused): per-bucket degree hist -> in-LDS scan -> row_ptr -> placement.
// One block owns its 256-node range exclusively: zero global atomics; csr
// writes land in a block-exclusive ~65KB window (full-line L2-local
// writebacks).
__global__ __launch_bounds__(NPB) void k_buildcsr(const int* __restrict__ boffB,
                                                  const int* __restrict__ bcnt,
                                                  const int* __restrict__ dstS,
                                                  const int* __restrict__ srcS,
                                                  const float* __restrict__ ewS,
                                                  int* __restrict__ row_ptr,
                                                  int2* __restrict__ csr,
                                                  int n_nodes, int n_edges) {
    __shared__ int hist[NPB];
    __shared__ int pre[NPB];
    int b = blockIdx.x;
    int t = threadIdx.x;
    hist[t] = 0;
    __syncthreads();
    int off = boffB[b];
    int end = off + bcnt[b];
    for (int i = off + t; i < end; i += NPB) atomicAdd(&hist[dstS[i] & (NPB - 1)], 1);
    __syncthreads();
    int v = hist[t];
    pre[t] = v;
    __syncthreads();
    for (int o = 1; o < NPB; o <<= 1) {
        int x = (t >= o) ? pre[t - o] : 0;
        __syncthreads();
        pre[t] += x;
        __syncthreads();
    }
    int ex = pre[t] - v;  // exclusive in-bucket prefix
    int node = b * NPB + t;
    if (node < n_nodes) row_ptr[node] = off + ex;
    if (node == n_nodes - 1) row_ptr[n_nodes] = n_edges;
    // zero pad so k_edge's clamped tail reads (deg-0 last nodes) are safe
    if (b == 0 && t < 8) csr[n_edges + t] = make_int2(0, 0);
    hist[t] = off + ex;  // reuse as cursor
    __syncthreads();
    for (int i = off + t; i < end; i += NPB) {
        int d = dstS[i];
        int p = atomicAdd(&hist[d & (NPB - 1)], 1);
        csr[p] = make_int2(srcS[i], __float_as_int(ewS[i]));
    }
}

// ---------------- GEMM + fused attention scores (streamed A) ----------------
__global__ __launch_bounds__(256) void k_gemm(const float* __restrict__ A,
                                              const float* __restrict__ B,
                                              float* __restrict__ C,
                                              const float* __restrict__ al,
                                              const float* __restrict__ ar,
                                              float* __restrict__ el,
                                              float* __restrict__ er, int n) {
    __shared__ float Bs[128 * 64];  // Bs[k][c]
    int t = threadIdx.x;
    int row0 = blockIdx.x * 64;
    int colbase = blockIdx.y * 64;

    // stage B strip
    {
        int c0 = (t & 15) * 4;
        int kr = t >> 4;  // 0..15
        for (int it = 0; it < 8; ++it) {
            int k = kr + it * 16;
            float4 v = *(const float4*)(B + (size_t)k * 128 + colbase + c0);
            *(float4*)(Bs + k * 64 + c0) = v;
        }
    }
    __syncthreads();

    int r0 = row0 + (t >> 4) * 4;
    int c0 = (t & 15) * 4;
    const float* Ar0 = A + (size_t)((r0 + 0) < n ? (r0 + 0) : 0) * 128;
    const float* Ar1 = A + (size_t)((r0 + 1) < n ? (r0 + 1) : 0) * 128;
    const float* Ar2 = A + (size_t)((r0 + 2) < n ? (r0 + 2) : 0) * 128;
    const float* Ar3 = A + (size_t)((r0 + 3) < n ? (r0 + 3) : 0) * 128;

    float acc[4][4];
#pragma unroll
    for (int i = 0; i < 4; i++)
#pragma unroll
        for (int j = 0; j < 4; j++) acc[i][j] = 0.f;

#pragma unroll 2
    for (int k = 0; k < 128; k += 4) {
        float4 a0 = *(const float4*)(Ar0 + k);
        float4 a1 = *(const float4*)(Ar1 + k);
        float4 a2 = *(const float4*)(Ar2 + k);
        float4 a3 = *(const float4*)(Ar3 + k);
#pragma unroll
        for (int kk = 0; kk < 4; kk++) {
            float4 b = *(const float4*)(Bs + (k + kk) * 64 + c0);
            float e0 = kk == 0 ? a0.x : kk == 1 ? a0.y : kk == 2 ? a0.z : a0.w;
            float e1 = kk == 0 ? a1.x : kk == 1 ? a1.y : kk == 2 ? a1.z : a1.w;
            float e2 = kk == 0 ? a2.x : kk == 1 ? a2.y : kk == 2 ? a2.z : a2.w;
            float e3 = kk == 0 ? a3.x : kk == 1 ? a3.y : kk == 2 ? a3.z : a3.w;
            acc[0][0] = fmaf(e0, b.x, acc[0][0]); acc[0][1] = fmaf(e0, b.y, acc[0][1]);
            acc[0][2] = fmaf(e0, b.z, acc[0][2]); acc[0][3] = fmaf(e0, b.w, acc[0][3]);
            acc[1][0] = fmaf(e1, b.x, acc[1][0]); acc[1][1] = fmaf(e1, b.y, acc[1][1]);
            acc[1][2] = fmaf(e1, b.z, acc[1][2]); acc[1][3] = fmaf(e1, b.w, acc[1][3]);
            acc[2][0] = fmaf(e2, b.x, acc[2][0]); acc[2][1] = fmaf(e2, b.y, acc[2][1]);
            acc[2][2] = fmaf(e2, b.z, acc[2][2]); acc[2][3] = fmaf(e2, b.w, acc[2][3]);
            acc[3][0] = fmaf(e3, b.x, acc[3][0]); acc[3][1] = fmaf(e3, b.y, acc[3][1]);
            acc[3][2] = fmaf(e3, b.z, acc[3][2]); acc[3][3] = fmaf(e3, b.w, acc[3][3]);
        }
    }

#pragma unroll
    for (int i = 0; i < 4; i++) {
        int r = r0 + i;
        if (r < n) {
            float4 v = make_float4(acc[i][0], acc[i][1], acc[i][2], acc[i][3]);
            *(float4*)(C + (size_t)r * 128 + colbase + c0) = v;
        }
    }

    // fused el/er: strip covers heads 2*by, 2*by+1; 8 consecutive lanes share
    // (row group, head) -> shfl reduce.
    {
        int hg = blockIdx.y * 2 + ((t >> 3) & 1);
        float4 a4 = *(const float4*)(al + hg * 32 + (t & 7) * 4);
        float4 b4 = *(const float4*)(ar + hg * 32 + (t & 7) * 4);
        float pel[4], per[4];
#pragma unroll
        for (int i = 0; i < 4; i++) {
            pel[i] = acc[i][0] * a4.x + acc[i][1] * a4.y + acc[i][2] * a4.z + acc[i][3] * a4.w;
            per[i] = acc[i][0] * b4.x + acc[i][1] * b4.y + acc[i][2] * b4.z + acc[i][3] * b4.w;
        }
#pragma unroll
        for (int m = 1; m < 8; m <<= 1) {
#pragma unroll
            for (int i = 0; i < 4; i++) {
                pel[i] += __shfl_xor(pel[i], m);
                per[i] += __shfl_xor(per[i], m);
            }
        }
        if ((t & 7) == 0) {
#pragma unroll
            for (int i = 0; i < 4; i++) {
                int r = r0 + i;
                if (r < n) {
                    el[(size_t)r * 4 + hg] = pel[i];
                    er[(size_t)r * 4 + hg] = per[i];
                }
            }
        }
    }
}

// ---------------- per-dst-node softmax + aggregate (8-wide MLP) ----------
// TWO nodes per wave (32-lane halves); lane li owns float4 li of the row,
// head h = li>>3. Latency-bound at width 4 (VALUBusy 29%, fetch 3.7 TB/s,
// VGPR 28): widen the basic block to 8 edges/iter. All 8 csr loads, then all
// 8 el, then all 8 feat4 gathers issue before any use — the compiler groups
// loads within one BB (proven in round-1 asm at width 4), giving 8-deep MLP
// without relying on cross-iteration scheduling (which hipcc defeats).
__global__ __launch_bounds__(256) void k_edge(const int* __restrict__ row_ptr,
                                              const int2* __restrict__ csr,
                                              const float* __restrict__ feat,
                                              const float* __restrict__ el,
                                              const float* __restrict__ er,
                                              const float* __restrict__ bias,
                                              float* __restrict__ out, int n) {
    int wv = threadIdx.x >> 6;
    int lane = threadIdx.x & 63;
    int sub = lane >> 5;   // which node of this wave's pair
    int li = lane & 31;    // feature lane
    int h = li >> 3;       // head
    int v = blockIdx.x * 8 + wv * 2 + sub;
    bool active = v < n;
    int vc = active ? v : n - 1;

    int start = row_ptr[vc];
    int end = active ? row_ptr[vc + 1] : start;
    float er_h = er[(size_t)vc * 4 + h];

    int myT = (end - start + 7) >> 3;
    int otherT = __shfl(myT, lane ^ 32);
    int maxT = myT > otherT ? myT : otherT;

    int last = end - 1;
    if (last < start) last = start;  // deg-0 half: clamped reads (csr pad is zeroed)

    float4 acc = make_float4(0.f, 0.f, 0.f, 0.f);
    float ssum = 0.f;
    const float4* feat4 = (const float4*)feat;

    for (int j = 0; j < maxT; ++j) {
        int i = start + j * 8;
        int idx[8];
        float msk[8];
#pragma unroll
        for (int k = 0; k < 8; ++k) {
            idx[k] = (i + k < last) ? i + k : last;
            msk[k] = (i + k < end) ? 1.f : 0.f;
        }
        int2 c[8];
#pragma unroll
        for (int k = 0; k < 8; ++k) c[k] = csr[idx[k]];
        float ev[8];
#pragma unroll
        for (int k = 0; k < 8; ++k) ev[k] = el[(size_t)c[k].x * 4 + h];
        float4 f[8];
#pragma unroll
        for (int k = 0; k < 8; ++k) f[k] = feat4[(size_t)c[k].x * 32 + li];
#pragma unroll
        for (int k = 0; k < 8; ++k) {
            float p = msk[k] * __expf(leaky(ev[k] + er_h));
            ssum += p;
            float w = p * __int_as_float(c[k].y);
            acc.x = fmaf(w, f[k].x, acc.x);
            acc.y = fmaf(w, f[k].y, acc.y);
            acc.z = fmaf(w, f[k].z, acc.z);
            acc.w = fmaf(w, f[k].w, acc.w);
        }
    }

    if (active) {
        float inv = 1.f / fmaxf(ssum, 1e-20f);
        float4 bv = *(const float4*)(bias + li * 4);
        float o0 = fmaf(acc.x, inv, bv.x);
        float o1 = fmaf(acc.y, inv, bv.y);
        float o2 = fmaf(acc.z, inv, bv.z);
        float o3 = fmaf(acc.w, inv, bv.w);
        o0 = o0 > 0.f ? o0 : __expf(o0) - 1.f;
        o1 = o1 > 0.f ? o1 : __expf(o1) - 1.f;
        o2 = o2 > 0.f ? o2 : __expf(o2) - 1.f;
        o3 = o3 > 0.f ? o3 : __expf(o3) - 1.f;
        *(float4*)(out + (size_t)v * 128 + li * 4) = make_float4(o0, o1, o2, o3);
    }
}

// ---------------- launch ----------------
extern "C" void kernel_launch(void* const* d_in, const int* in_sizes, int n_in,
                              void* d_out, int out_size, void* d_ws, size_t ws_size,
                              hipStream_t stream) {
    int n_nodes = in_sizes[0] / 128;
    int n_edges = in_sizes[1];

    const float* in_feat = (const float*)d_in[0];
    const float* ew = (const float*)d_in[1];
    const int* src = (const int*)d_in[2];
    const int* dst = (const int*)d_in[3];
    const float* W0 = (const float*)d_in[4];
    const float* al0 = (const float*)d_in[5];
    const float* ar0 = (const float*)d_in[6];
    const float* b0 = (const float*)d_in[7];
    const float* W1 = (const float*)d_in[8];
    const float* al1 = (const float*)d_in[9];
    const float* ar1 = (const float*)d_in[10];
    const float* b1 = (const float*)d_in[11];
    float* out = (float*)d_out;

    char* w = (char*)d_ws;
    auto alloc = [&](size_t bytes) {
        char* p = w;
        w += (bytes + 255) & ~(size_t)255;
        return p;
    };
    float* feat = (float*)alloc((size_t)n_nodes * 128 * 4);
    float* h1 = (float*)alloc((size_t)n_nodes * 128 * 4);
    float* el = (float*)alloc((size_t)n_nodes * 4 * 4);
    float* er = (float*)alloc((size_t)n_nodes * 4 * 4);
    int* row_ptr = (int*)alloc(((size_t)n_nodes + 1) * 4);
    int* bcnt = (int*)alloc(MAXB * 4);
    int* boffB = (int*)alloc(MAXB * 4);
    int* bcur = (int*)alloc(MAXB * 4);
    int2* csr = (int2*)alloc((size_t)n_edges * 8 + 64);  // +pad for clamped tail reads

    // SoA staging overlays feat: staging (written k_bin, read k_buildcsr) is
    // dead before k_gemm writes feat (stream-ordered). 3*E*4 = 38.4MB <= 51.2MB.
    int* dstS = (int*)feat;
    int* srcS = dstS + n_edges;
    float* ewS = (float*)(srcS + n_edges);

    int tb = 256;
    int nb2 = (n_nodes + NPB - 1) / NPB;  // buckets (<= MAXB for n<=131072)

    // CSR build: bucketed counting sort (rebuilt every call)
    k_zero<<<(MAXB + tb - 1) / tb, tb, 0, stream>>>(bcnt, nb2);
    k_bcount<<<256, tb, 0, stream>>>(dst, bcnt, n_edges, nb2);
    k_bscan<<<1, MAXB, 0, stream>>>(bcnt, boffB, bcur, nb2);
    int a1_grid = 256;
    int chunk = (n_edges + a1_grid - 1) / a1_grid;
    k_bin<<<a1_grid, A1_BS, 0, stream>>>(src, dst, ew, bcur, dstS, srcS, ewS, n_edges, chunk, nb2);
    k_buildcsr<<<nb2, NPB, 0, stream>>>(boffB, bcnt, dstS, srcS, ewS, row_ptr, csr,
                                        n_nodes, n_edges);

    dim3 gg((n_nodes + 63) / 64, 2);
    int ge = (n_nodes + 7) / 8;

    // layer 1
    k_gemm<<<gg, 256, 0, stream>>>(in_feat, W0, feat, al0, ar0, el, er, n_nodes);
    k_edge<<<ge, 256, 0, stream>>>(row_ptr, csr, feat, el, er, b0, h1, n_nodes);

    // layer 2
    k_gemm<<<gg, 256, 0, stream>>>(h1, W1, feat, al1, ar1, el, er, n_nodes);
    k_edge<<<ge, 256, 0, stream>>>(row_ptr, csr, feat, el, er, b1, out, n_nodes);
}

// Round 4
// 994.922 us; speedup vs baseline: 1.0301x; 1.0119x over previous
//
#include <hip/hip_runtime.h>
#include <math.h>

#define NEG_SLOPE 0.2f
#define NPB 256   // nodes per bucket (dst >> 8)
#define MAXB 512  // max buckets => supports n_nodes <= 131072 (bench: 100000 -> 391)
#define A1_BS 512

static __device__ __forceinline__ float leaky(float x) { return fmaxf(x, NEG_SLOPE * x); }

// ---------------- misc ----------------
__global__ void k_zero(int* p, int n) {
    int i = blockIdx.x * blockDim.x + threadIdx.x;
    if (i < n) p[i] = 0;
}

// ---------------- bucketed counting sort CSR build ----------------
// Buckets = 256-node ranges. All heavy atomics are LDS-local; all heavy global
// writes are to per-block-exclusive contiguous ranges (lines fill while
// L2-resident). CSR is AoS int2 (src, ew-bits): one 8B load per edge in k_edge.

// Pass A0: global bucket histogram (LDS pre-aggregated).
__global__ __launch_bounds__(256) void k_bcount(const int* __restrict__ dst,
                                                int* __restrict__ bcnt, int n_edges, int nb) {
    __shared__ int h[MAXB];
    for (int i = threadIdx.x; i < nb; i += blockDim.x) h[i] = 0;
    __syncthreads();
    int stride = gridDim.x * blockDim.x;
    for (int e = blockIdx.x * blockDim.x + threadIdx.x; e < n_edges; e += stride)
        atomicAdd(&h[dst[e] >> 8], 1);
    __syncthreads();
    for (int i = threadIdx.x; i < nb; i += blockDim.x)
        if (h[i]) atomicAdd(&bcnt[i], h[i]);
}

// Bucket exclusive scan (nb <= MAXB, single block).
__global__ __launch_bounds__(MAXB) void k_bscan(const int* __restrict__ bcnt,
                                                int* __restrict__ boffB,
                                                int* __restrict__ bcur, int nb) {
    __shared__ int s[MAXB];
    int t = threadIdx.x;
    int v = (t < nb) ? bcnt[t] : 0;
    s[t] = v;
    __syncthreads();
    for (int off = 1; off < MAXB; off <<= 1) {
        int x = (t >= off) ? s[t - off] : 0;
        __syncthreads();
        s[t] += x;
        __syncthreads();
    }
    if (t < nb) {
        int ex = s[t] - v;
        boffB[t] = ex;
        bcur[t] = ex;
    }
}

// Pass A1: bin edges into bucket-grouped SoA staging. Each block counts its
// chunk per bucket in LDS, reserves a contiguous exclusive slice per bucket
// (one global atomic per block x bucket), then writes dense into its slices.
__global__ __launch_bounds__(A1_BS) void k_bin(const int* __restrict__ src,
                                               const int* __restrict__ dst,
                                               const float* __restrict__ ew,
                                               int* __restrict__ bcur,
                                               int* __restrict__ dstS,
                                               int* __restrict__ srcS,
                                               float* __restrict__ ewS,
                                               int n_edges, int chunk, int nb) {
    __shared__ int cnt[MAXB];
    __shared__ int base[MAXB];
    int t = threadIdx.x;
    int e0 = blockIdx.x * chunk;
    int e1 = e0 + chunk;
    if (e1 > n_edges) e1 = n_edges;
    for (int i = t; i < nb; i += A1_BS) cnt[i] = 0;
    __syncthreads();
    for (int e = e0 + t; e < e1; e += A1_BS) atomicAdd(&cnt[dst[e] >> 8], 1);
    __syncthreads();
    for (int i = t; i < nb; i += A1_BS) {
        int c = cnt[i];
        base[i] = c ? atomicAdd(&bcur[i], c) : 0;
        cnt[i] = 0;  // reuse as local rank cursor
    }
    __syncthreads();
    for (int e = e0 + t; e < e1; e += A1_BS) {
        int d = dst[e];
        int b = d >> 8;
        int p = base[b] + atomicAdd(&cnt[b], 1);
        dstS[p] = d;
        srcS[p] = src[e];
        ewS[p] = ew[e];
    }
}

// Pass B (fused): per-bucket degree hist -> in-LDS scan -> row_ptr -> placement.
// One block owns its 256-node range exclusively: zero global atomics; csr
// writes land in a block-exclusive ~65KB window (full-line L2-local
// writebacks).
__global__ __launch_bounds__(NPB) void k_buildcsr(const int* __restrict__ boffB,
                                                  const int* __restrict__ bcnt,
                                                  const int* __restrict__ dstS,
                                                  const int* __restrict__ srcS,
                                                  const float* __restrict__ ewS,
                                                  int* __restrict__ row_ptr,
                                                  int2* __restrict__ csr,
                                                  int n_nodes, int n_edges) {
    __shared__ int hist[NPB];
    __shared__ int pre[NPB];
    int b = blockIdx.x;
    int t = threadIdx.x;
    hist[t] = 0;
    __syncthreads();
    int off = boffB[b];
    int end = off + bcnt[b];
    for (int i = off + t; i < end; i += NPB) atomicAdd(&hist[dstS[i] & (NPB - 1)], 1);
    __syncthreads();
    int v = hist[t];
    pre[t] = v;
    __syncthreads();
    for (int o = 1; o < NPB; o <<= 1) {
        int x = (t >= o) ? pre[t - o] : 0;
        __syncthreads();
        pre[t] += x;
        __syncthreads();
    }
    int ex = pre[t] - v;  // exclusive in-bucket prefix
    int node = b * NPB + t;
    if (node < n_nodes) row_ptr[node] = off + ex;
    if (node == n_nodes - 1) row_ptr[n_nodes] = n_edges;
    // zero pad so k_edge's clamped tail reads (deg-0 last nodes) are safe
    if (b == 0 && t < 8) csr[n_edges + t] = make_int2(0, 0);
    hist[t] = off + ex;  // reuse as cursor
    __syncthreads();
    for (int i = off + t; i < end; i += NPB) {
        int d = dstS[i];
        int p = atomicAdd(&hist[d & (NPB - 1)], 1);
        csr[p] = make_int2(srcS[i], __float_as_int(ewS[i]));
    }
}

// ---------------- GEMM + fused attention scores (streamed A) ----------------
__global__ __launch_bounds__(256) void k_gemm(const float* __restrict__ A,
                                              const float* __restrict__ B,
                                              float* __restrict__ C,
                                              const float* __restrict__ al,
                                              const float* __restrict__ ar,
                                              float* __restrict__ el,
                                              float* __restrict__ er, int n) {
    __shared__ float Bs[128 * 64];  // Bs[k][c]
    int t = threadIdx.x;
    int row0 = blockIdx.x * 64;
    int colbase = blockIdx.y * 64;

    // stage B strip
    {
        int c0 = (t & 15) * 4;
        int kr = t >> 4;  // 0..15
        for (int it = 0; it < 8; ++it) {
            int k = kr + it * 16;
            float4 v = *(const float4*)(B + (size_t)k * 128 + colbase + c0);
            *(float4*)(Bs + k * 64 + c0) = v;
        }
    }
    __syncthreads();

    int r0 = row0 + (t >> 4) * 4;
    int c0 = (t & 15) * 4;
    const float* Ar0 = A + (size_t)((r0 + 0) < n ? (r0 + 0) : 0) * 128;
    const float* Ar1 = A + (size_t)((r0 + 1) < n ? (r0 + 1) : 0) * 128;
    const float* Ar2 = A + (size_t)((r0 + 2) < n ? (r0 + 2) : 0) * 128;
    const float* Ar3 = A + (size_t)((r0 + 3) < n ? (r0 + 3) : 0) * 128;

    float acc[4][4];
#pragma unroll
    for (int i = 0; i < 4; i++)
#pragma unroll
        for (int j = 0; j < 4; j++) acc[i][j] = 0.f;

#pragma unroll 2
    for (int k = 0; k < 128; k += 4) {
        float4 a0 = *(const float4*)(Ar0 + k);
        float4 a1 = *(const float4*)(Ar1 + k);
        float4 a2 = *(const float4*)(Ar2 + k);
        float4 a3 = *(const float4*)(Ar3 + k);
#pragma unroll
        for (int kk = 0; kk < 4; kk++) {
            float4 b = *(const float4*)(Bs + (k + kk) * 64 + c0);
            float e0 = kk == 0 ? a0.x : kk == 1 ? a0.y : kk == 2 ? a0.z : a0.w;
            float e1 = kk == 0 ? a1.x : kk == 1 ? a1.y : kk == 2 ? a1.z : a1.w;
            float e2 = kk == 0 ? a2.x : kk == 1 ? a2.y : kk == 2 ? a2.z : a2.w;
            float e3 = kk == 0 ? a3.x : kk == 1 ? a3.y : kk == 2 ? a3.z : a3.w;
            acc[0][0] = fmaf(e0, b.x, acc[0][0]); acc[0][1] = fmaf(e0, b.y, acc[0][1]);
            acc[0][2] = fmaf(e0, b.z, acc[0][2]); acc[0][3] = fmaf(e0, b.w, acc[0][3]);
            acc[1][0] = fmaf(e1, b.x, acc[1][0]); acc[1][1] = fmaf(e1, b.y, acc[1][1]);
            acc[1][2] = fmaf(e1, b.z, acc[1][2]); acc[1][3] = fmaf(e1, b.w, acc[1][3]);
            acc[2][0] = fmaf(e2, b.x, acc[2][0]); acc[2][1] = fmaf(e2, b.y, acc[2][1]);
            acc[2][2] = fmaf(e2, b.z, acc[2][2]); acc[2][3] = fmaf(e2, b.w, acc[2][3]);
            acc[3][0] = fmaf(e3, b.x, acc[3][0]); acc[3][1] = fmaf(e3, b.y, acc[3][1]);
            acc[3][2] = fmaf(e3, b.z, acc[3][2]); acc[3][3] = fmaf(e3, b.w, acc[3][3]);
        }
    }

#pragma unroll
    for (int i = 0; i < 4; i++) {
        int r = r0 + i;
        if (r < n) {
            float4 v = make_float4(acc[i][0], acc[i][1], acc[i][2], acc[i][3]);
            *(float4*)(C + (size_t)r * 128 + colbase + c0) = v;
        }
    }

    // fused el/er: strip covers heads 2*by, 2*by+1; 8 consecutive lanes share
    // (row group, head) -> shfl reduce.
    {
        int hg = blockIdx.y * 2 + ((t >> 3) & 1);
        float4 a4 = *(const float4*)(al + hg * 32 + (t & 7) * 4);
        float4 b4 = *(const float4*)(ar + hg * 32 + (t & 7) * 4);
        float pel[4], per[4];
#pragma unroll
        for (int i = 0; i < 4; i++) {
            pel[i] = acc[i][0] * a4.x + acc[i][1] * a4.y + acc[i][2] * a4.z + acc[i][3] * a4.w;
            per[i] = acc[i][0] * b4.x + acc[i][1] * b4.y + acc[i][2] * b4.z + acc[i][3] * b4.w;
        }
#pragma unroll
        for (int m = 1; m < 8; m <<= 1) {
#pragma unroll
            for (int i = 0; i < 4; i++) {
                pel[i] += __shfl_xor(pel[i], m);
                per[i] += __shfl_xor(per[i], m);
            }
        }
        if ((t & 7) == 0) {
#pragma unroll
            for (int i = 0; i < 4; i++) {
                int r = r0 + i;
                if (r < n) {
                    el[(size_t)r * 4 + hg] = pel[i];
                    er[(size_t)r * 4 + hg] = per[i];
                }
            }
        }
    }
}

// ---------------- per-dst-node softmax + aggregate (8-wide MLP, pinned) ----
// TWO nodes per wave (32-lane halves); lane li owns float4 li of the row,
// head h = li>>3. Rounds 1-3 all landed at VGPR=32 / 29% VALUBusy / 3.8 TB/s:
// the occupancy-driven scheduler sinks every gather next to its use (no MLP).
// Two levers force clustering:
//   (a) __launch_bounds__(256, 2): occupancy target 2 waves/EU -> ~256 VGPR
//       budget, so 8 in-flight {csr,el,feat4} groups fit in registers.
//   (b) sched_barrier(0) between the load block and compute block: machine
//       scheduler cannot sink loads across it.
// Expected flip: latency-bound -> beyond-L2-fetch-bound (~912MB / 6.3TB/s).
__global__ __launch_bounds__(256, 2) void k_edge(const int* __restrict__ row_ptr,
                                                 const int2* __restrict__ csr,
                                                 const float* __restrict__ feat,
                                                 const float* __restrict__ el,
                                                 const float* __restrict__ er,
                                                 const float* __restrict__ bias,
                                                 float* __restrict__ out, int n) {
    int wv = threadIdx.x >> 6;
    int lane = threadIdx.x & 63;
    int sub = lane >> 5;   // which node of this wave's pair
    int li = lane & 31;    // feature lane
    int h = li >> 3;       // head
    int v = blockIdx.x * 8 + wv * 2 + sub;
    bool active = v < n;
    int vc = active ? v : n - 1;

    int start = row_ptr[vc];
    int end = active ? row_ptr[vc + 1] : start;
    float er_h = er[(size_t)vc * 4 + h];

    int myT = (end - start + 7) >> 3;
    int otherT = __shfl(myT, lane ^ 32);
    int maxT = myT > otherT ? myT : otherT;

    int last = end - 1;
    if (last < start) last = start;  // deg-0 half: clamped reads (csr pad is zeroed)

    float4 acc = make_float4(0.f, 0.f, 0.f, 0.f);
    float ssum = 0.f;
    const float4* feat4 = (const float4*)feat;

    for (int j = 0; j < maxT; ++j) {
        int i = start + j * 8;
        int idx[8];
        float msk[8];
#pragma unroll
        for (int k = 0; k < 8; ++k) {
            idx[k] = (i + k < last) ? i + k : last;
            msk[k] = (i + k < end) ? 1.f : 0.f;
        }
        // ---- load block: 8 csr, 8 el, 8 feat4 all issued before any use ----
        int2 c[8];
#pragma unroll
        for (int k = 0; k < 8; ++k) c[k] = csr[idx[k]];
        float ev[8];
#pragma unroll
        for (int k = 0; k < 8; ++k) ev[k] = el[(size_t)c[k].x * 4 + h];
        float4 f[8];
#pragma unroll
        for (int k = 0; k < 8; ++k) f[k] = feat4[(size_t)c[k].x * 32 + li];
        // fence: scheduler may not sink the loads above into the compute below
        __builtin_amdgcn_sched_barrier(0);
        // ---- compute block: p needs only ev (partial waits); f drains last --
#pragma unroll
        for (int k = 0; k < 8; ++k) {
            float p = msk[k] * __expf(leaky(ev[k] + er_h));
            ssum += p;
            float w = p * __int_as_float(c[k].y);
            acc.x = fmaf(w, f[k].x, acc.x);
            acc.y = fmaf(w, f[k].y, acc.y);
            acc.z = fmaf(w, f[k].z, acc.z);
            acc.w = fmaf(w, f[k].w, acc.w);
        }
    }

    if (active) {
        float inv = 1.f / fmaxf(ssum, 1e-20f);
        float4 bv = *(const float4*)(bias + li * 4);
        float o0 = fmaf(acc.x, inv, bv.x);
        float o1 = fmaf(acc.y, inv, bv.y);
        float o2 = fmaf(acc.z, inv, bv.z);
        float o3 = fmaf(acc.w, inv, bv.w);
        o0 = o0 > 0.f ? o0 : __expf(o0) - 1.f;
        o1 = o1 > 0.f ? o1 : __expf(o1) - 1.f;
        o2 = o2 > 0.f ? o2 : __expf(o2) - 1.f;
        o3 = o3 > 0.f ? o3 : __expf(o3) - 1.f;
        *(float4*)(out + (size_t)v * 128 + li * 4) = make_float4(o0, o1, o2, o3);
    }
}

// ---------------- launch ----------------
extern "C" void kernel_launch(void* const* d_in, const int* in_sizes, int n_in,
                              void* d_out, int out_size, void* d_ws, size_t ws_size,
                              hipStream_t stream) {
    int n_nodes = in_sizes[0] / 128;
    int n_edges = in_sizes[1];

    const float* in_feat = (const float*)d_in[0];
    const float* ew = (const float*)d_in[1];
    const int* src = (const int*)d_in[2];
    const int* dst = (const int*)d_in[3];
    const float* W0 = (const float*)d_in[4];
    const float* al0 = (const float*)d_in[5];
    const float* ar0 = (const float*)d_in[6];
    const float* b0 = (const float*)d_in[7];
    const float* W1 = (const float*)d_in[8];
    const float* al1 = (const float*)d_in[9];
    const float* ar1 = (const float*)d_in[10];
    const float* b1 = (const float*)d_in[11];
    float* out = (float*)d_out;

    char* w = (char*)d_ws;
    auto alloc = [&](size_t bytes) {
        char* p = w;
        w += (bytes + 255) & ~(size_t)255;
        return p;
    };
    float* feat = (float*)alloc((size_t)n_nodes * 128 * 4);
    float* h1 = (float*)alloc((size_t)n_nodes * 128 * 4);
    float* el = (float*)alloc((size_t)n_nodes * 4 * 4);
    float* er = (float*)alloc((size_t)n_nodes * 4 * 4);
    int* row_ptr = (int*)alloc(((size_t)n_nodes + 1) * 4);
    int* bcnt = (int*)alloc(MAXB * 4);
    int* boffB = (int*)alloc(MAXB * 4);
    int* bcur = (int*)alloc(MAXB * 4);
    int2* csr = (int2*)alloc((size_t)n_edges * 8 + 64);  // +pad for clamped tail reads

    // SoA staging overlays feat: staging (written k_bin, read k_buildcsr) is
    // dead before k_gemm writes feat (stream-ordered). 3*E*4 = 38.4MB <= 51.2MB.
    int* dstS = (int*)feat;
    int* srcS = dstS + n_edges;
    float* ewS = (float*)(srcS + n_edges);

    int tb = 256;
    int nb2 = (n_nodes + NPB - 1) / NPB;  // buckets (<= MAXB for n<=131072)

    // CSR build: bucketed counting sort (rebuilt every call)
    k_zero<<<(MAXB + tb - 1) / tb, tb, 0, stream>>>(bcnt, nb2);
    k_bcount<<<256, tb, 0, stream>>>(dst, bcnt, n_edges, nb2);
    k_bscan<<<1, MAXB, 0, stream>>>(bcnt, boffB, bcur, nb2);
    int a1_grid = 256;
    int chunk = (n_edges + a1_grid - 1) / a1_grid;
    k_bin<<<a1_grid, A1_BS, 0, stream>>>(src, dst, ew, bcur, dstS, srcS, ewS, n_edges, chunk, nb2);
    k_buildcsr<<<nb2, NPB, 0, stream>>>(boffB, bcnt, dstS, srcS, ewS, row_ptr, csr,
                                        n_nodes, n_edges);

    dim3 gg((n_nodes + 63) / 64, 2);
    int ge = (n_nodes + 7) / 8;

    // layer 1
    k_gemm<<<gg, 256, 0, stream>>>(in_feat, W0, feat, al0, ar0, el, er, n_nodes);
    k_edge<<<ge, 256, 0, stream>>>(row_ptr, csr, feat, el, er, b0, h1, n_nodes);

    // layer 2
    k_gemm<<<gg, 256, 0, stream>>>(h1, W1, feat, al1, ar1, el, er, n_nodes);
    k_edge<<<ge, 256, 0, stream>>>(row_ptr, csr, feat, el, er, b1, out, n_nodes);
}